// Round 14
// baseline (2727.467 us; speedup 1.0000x reference)
//
#include <hip/hip_runtime.h>
#include <hip/hip_bf16.h>
#include <stdint.h>

#define HD 4096
#define VD 32000
#define BT 2048        // B*T rows
#define TT 512
#define IGNORE_IDX (-100)

// fp8 main GEMM geometry: 256x256 block, K-tile 128 (one MFMA K), 8 waves of 128x64
#define BM 256
#define BN 256
#define BKT8 128
#define KT8 (HD / BKT8)        // 32
#define NB (VD / BN)           // 125
#define MB (BT / BM)           // 8
#define NWG2 (MB * NB * 2)     // 2000

#define NCHUNK (VD / 64)       // 500

typedef __attribute__((ext_vector_type(8))) short short8;
typedef __attribute__((ext_vector_type(4))) float f32x4;
typedef __attribute__((ext_vector_type(8))) int i32x8;

__device__ __forceinline__ uint16_t f2bf(float f) {
    uint32_t u = __float_as_uint(f);
    u += 0x7FFFu + ((u >> 16) & 1u);
    return (uint16_t)(u >> 16);
}

__device__ __forceinline__ void gload16(const void* g, void* l) {
    __builtin_amdgcn_global_load_lds(
        (const __attribute__((address_space(1))) void*)g,
        (__attribute__((address_space(3))) void*)l, 16, 0, 0);
}

#define SBAR __builtin_amdgcn_sched_barrier(0)

// ---------------- kernel 0a: convert x inputs f32 -> fp8 e4m3 (scale 1.0) ----------------
__global__ void convert_x_fp8(const float* __restrict__ x0, const float* __restrict__ x1,
                              uint8_t* __restrict__ xq) {
    const int64_t n8 = (int64_t)BT * HD / 8;
    uint2* o0 = (uint2*)xq;
    uint2* o1 = (uint2*)(xq + (size_t)BT * HD);
    for (int64_t i = blockIdx.x * (int64_t)blockDim.x + threadIdx.x; i < n8;
         i += (int64_t)gridDim.x * blockDim.x) {
        float4 a = ((const float4*)x0)[2 * i];
        float4 b = ((const float4*)x0)[2 * i + 1];
        int lo = __builtin_amdgcn_cvt_pk_fp8_f32(a.x, a.y, 0, false);
        lo     = __builtin_amdgcn_cvt_pk_fp8_f32(a.z, a.w, lo, true);
        int hi = __builtin_amdgcn_cvt_pk_fp8_f32(b.x, b.y, 0, false);
        hi     = __builtin_amdgcn_cvt_pk_fp8_f32(b.z, b.w, hi, true);
        o0[i] = make_uint2((unsigned)lo, (unsigned)hi);
        a = ((const float4*)x1)[2 * i];
        b = ((const float4*)x1)[2 * i + 1];
        lo = __builtin_amdgcn_cvt_pk_fp8_f32(a.x, a.y, 0, false);
        lo = __builtin_amdgcn_cvt_pk_fp8_f32(a.z, a.w, lo, true);
        hi = __builtin_amdgcn_cvt_pk_fp8_f32(b.x, b.y, 0, false);
        hi = __builtin_amdgcn_cvt_pk_fp8_f32(b.z, b.w, hi, true);
        o1[i] = make_uint2((unsigned)lo, (unsigned)hi);
    }
}

// ---------------- kernel 0b: convert weights f32 -> fp8 e4m3, pre-scaled by 64 ----------------
// (dequant 2^-6 folded into the MFMA's B scale operand)
__global__ void convert_w_fp8(const float* __restrict__ w0, const float* __restrict__ w1,
                              uint8_t* __restrict__ wq) {
    const int64_t n8 = (int64_t)VD * HD / 8;
    uint2* o0 = (uint2*)wq;
    uint2* o1 = (uint2*)(wq + (size_t)VD * HD);
    for (int64_t i = blockIdx.x * (int64_t)blockDim.x + threadIdx.x; i < n8;
         i += (int64_t)gridDim.x * blockDim.x) {
        float4 a = ((const float4*)w0)[2 * i];
        float4 b = ((const float4*)w0)[2 * i + 1];
        int lo = __builtin_amdgcn_cvt_pk_fp8_f32(a.x * 64.f, a.y * 64.f, 0, false);
        lo     = __builtin_amdgcn_cvt_pk_fp8_f32(a.z * 64.f, a.w * 64.f, lo, true);
        int hi = __builtin_amdgcn_cvt_pk_fp8_f32(b.x * 64.f, b.y * 64.f, 0, false);
        hi     = __builtin_amdgcn_cvt_pk_fp8_f32(b.z * 64.f, b.w * 64.f, hi, true);
        o0[i] = make_uint2((unsigned)lo, (unsigned)hi);
        a = ((const float4*)w1)[2 * i];
        b = ((const float4*)w1)[2 * i + 1];
        lo = __builtin_amdgcn_cvt_pk_fp8_f32(a.x * 64.f, a.y * 64.f, 0, false);
        lo = __builtin_amdgcn_cvt_pk_fp8_f32(a.z * 64.f, a.w * 64.f, lo, true);
        hi = __builtin_amdgcn_cvt_pk_fp8_f32(b.x * 64.f, b.y * 64.f, 0, false);
        hi = __builtin_amdgcn_cvt_pk_fp8_f32(b.z * 64.f, b.w * 64.f, hi, true);
        o1[i] = make_uint2((unsigned)lo, (unsigned)hi);
    }
}

// load one 32-byte fp8 fragment (k = kg*32..+31) from swizzled LDS (2x b128)
__device__ __forceinline__ i32x8 ld_frag(const char* pe, const char* po, int off) {
    uint4 lo = *(const uint4*)(pe + off);
    uint4 hi = *(const uint4*)(po + off);
    i32x8 r;
    r[0] = lo.x; r[1] = lo.y; r[2] = lo.z; r[3] = lo.w;
    r[4] = hi.x; r[5] = hi.y; r[6] = hi.z; r[7] = hi.w;
    return r;
}

// 8 MFMA (2 mi x 4 ni), K=128, uniform scales: A x1.0 (127), B x2^-6 (121)
__device__ __forceinline__ void mfma8(
    const i32x8& a0, const i32x8& a1, const i32x8 (&bfr)[4],
    f32x4* acc0, f32x4* acc1)
{
    __builtin_amdgcn_s_setprio(1);
#pragma unroll
    for (int ni = 0; ni < 4; ++ni)
        acc0[ni] = __builtin_amdgcn_mfma_scale_f32_16x16x128_f8f6f4(
            a0, bfr[ni], acc0[ni], 0, 0, 0, 127, 0, 121);
#pragma unroll
    for (int ni = 0; ni < 4; ++ni)
        acc1[ni] = __builtin_amdgcn_mfma_scale_f32_16x16x128_f8f6f4(
            a1, bfr[ni], acc1[ni], 0, 0, 0, 127, 0, 121);
    __builtin_amdgcn_s_setprio(0);
}

// ---------------- fp8 tile body: R4's audited 4-phase counted-vmcnt ledger ----------------
// Stage order (tile t stages t+1): ph0 B j0,j1 ; ph1 B j2,j3 ; ph2 A j0,j1 ; ph3 A j2,j3.
// Waits: ph1-end vmcnt(4) retires prev A j2,j3; ph3-end vmcnt(2) retires B + A j0,j1.
template<int CUR>
__device__ __forceinline__ void tile8_body(
    int t,
    const uint8_t* __restrict__ agp, const uint8_t* __restrict__ bgp,
    char* aLdst, char* bLdst,
    const char* pAe, const char* pAo, const char* pBe, const char* pBo,
    f32x4 (&acc)[8][4])
{
    constexpr int CB  = CUR * 32768;
    constexpr int NXB = (CUR ^ 1) * 32768;
    const bool more = (t + 1) < KT8;
    const int ko = (t + 1) * BKT8;

    i32x8 bfr[4];
    i32x8 a0, a1;

#define BARR do { SBAR; __builtin_amdgcn_s_barrier(); SBAR; } while (0)

    // ---------- phase 0: B frags + A mi0,1 ; stage B j0,j1 ----------
#pragma unroll
    for (int ni = 0; ni < 4; ++ni)
        bfr[ni] = ld_frag(pBe, pBo, ni * 2048 + CB);
    a0 = ld_frag(pAe, pAo, 0 * 2048 + CB);
    a1 = ld_frag(pAe, pAo, 1 * 2048 + CB);
    if (more) {
        gload16(bgp + (size_t)(0 * 32) * HD + ko, bLdst + NXB + 0 * 4096);
        gload16(bgp + (size_t)(1 * 32) * HD + ko, bLdst + NXB + 1 * 4096);
    }
    BARR;
    mfma8(a0, a1, bfr, acc[0], acc[1]);
    BARR;

    // ---------- phase 1: A mi2,3 ; stage B j2,j3 ; vmcnt(4|0) ----------
    a0 = ld_frag(pAe, pAo, 2 * 2048 + CB);
    a1 = ld_frag(pAe, pAo, 3 * 2048 + CB);
    if (more) {
        gload16(bgp + (size_t)(2 * 32) * HD + ko, bLdst + NXB + 2 * 4096);
        gload16(bgp + (size_t)(3 * 32) * HD + ko, bLdst + NXB + 3 * 4096);
    }
    BARR;
    mfma8(a0, a1, bfr, acc[2], acc[3]);
    SBAR;
    if (more) { asm volatile("s_waitcnt vmcnt(4)" ::: "memory"); }
    else      { asm volatile("s_waitcnt vmcnt(0)" ::: "memory"); }
    SBAR;
    BARR;

    // ---------- phase 2: A mi4,5 ; stage A j0,j1 ----------
    a0 = ld_frag(pAe, pAo, 4 * 2048 + CB);
    a1 = ld_frag(pAe, pAo, 5 * 2048 + CB);
    if (more) {
        gload16(agp + (size_t)(0 * 32) * HD + ko, aLdst + NXB + 0 * 4096);
        gload16(agp + (size_t)(1 * 32) * HD + ko, aLdst + NXB + 1 * 4096);
    }
    BARR;
    mfma8(a0, a1, bfr, acc[4], acc[5]);
    BARR;

    // ---------- phase 3: A mi6,7 ; stage A j2,j3 ; vmcnt(2|0) ----------
    a0 = ld_frag(pAe, pAo, 6 * 2048 + CB);
    a1 = ld_frag(pAe, pAo, 7 * 2048 + CB);
    if (more) {
        gload16(agp + (size_t)(2 * 32) * HD + ko, aLdst + NXB + 2 * 4096);
        gload16(agp + (size_t)(3 * 32) * HD + ko, aLdst + NXB + 3 * 4096);
    }
    BARR;
    mfma8(a0, a1, bfr, acc[6], acc[7]);
    SBAR;
    if (more) { asm volatile("s_waitcnt vmcnt(2)" ::: "memory"); }
    else      { asm volatile("s_waitcnt vmcnt(0)" ::: "memory"); }
    SBAR;
    BARR;
#undef BARR
}

// ---------------- kernel 1 (main): 256x256 MX-fp8 GEMM + LSE partials ----------------
__global__ __launch_bounds__(512, 2) void gemm_lse_fp8(
    const uint8_t* __restrict__ xq, const uint8_t* __restrict__ wq,
    const float* __restrict__ b0, const float* __restrict__ b1,
    const int* __restrict__ target,
    float* __restrict__ partials, float* __restrict__ tgtlog)
{
    __shared__ uint8_t As[2 * BM * BKT8];  // 64 KB (2 buffers of 32 KB)
    __shared__ uint8_t Bs[2 * BN * BKT8];  // 64 KB

    const int orig = blockIdx.x;
    const int wgid = (orig & 7) * (NWG2 / 8) + (orig >> 3);
    const int mb    = wgid & 7;
    const int rest  = wgid >> 3;
    const int nb    = rest % NB;
    const int model = rest / NB;

    const uint8_t* xb = xq + (size_t)model * BT * HD;
    const uint8_t* wb = wq + (size_t)model * VD * HD;
    const float* bias = model ? b1 : b0;

    const int row0 = mb * BM;
    const int c0   = nb * BN;

    const int tid    = threadIdx.x;
    const int lane   = tid & 63;
    const int wid    = tid >> 6;       // 0..7
    const int wr     = wid >> 2;       // 0..1  (M half: 128 rows)
    const int wc     = wid & 3;        // 0..3  (N quarter: 64 cols)

    const int lane15 = lane & 15;
    const int kg     = lane >> 4;      // 0..3: k-block (32 fp8 elems each)

    // staging (R5-verified pattern): 1KB chunk = 8 rows x 128B; lane l -> row l>>3,
    // stored slot l&7; global source slot = (l&7)^(l>>3). LDS dest linear.
    const int srow8 = lane >> 3;
    const int slot  = (lane & 7) ^ srow8;
    const uint8_t* agp = xb + (size_t)(row0 + wr * 128 + wc * 8 + srow8) * HD + slot * 16;
    const int bq = wr * 2 + (wc & 1);
    const uint8_t* bgp = wb + (size_t)(c0 + (wc >> 1) * 128 + bq * 8 + srow8) * HD + slot * 16;
    char* aLdst = (char*)As + wr * 16384 + wc * 1024;          // + j*4096 + buf*32768
    char* bLdst = (char*)Bs + (wc >> 1) * 16384 + bq * 1024;   // + j*4096 + buf*32768

    // fragment read bases: frag k-slots 2kg (bytes 0-15 of block) and 2kg+1 (16-31),
    // swizzled by XOR (row&7); per-mi/ni +2048 (16 rows x 128B); +buf*32768.
    const int row_a = wr * 128 + lane15;
    const int row_b = wc * 64 + lane15;
    const char* pAe = (const char*)As + row_a * 128 + ((( 2 * kg    ) ^ (row_a & 7)) << 4);
    const char* pAo = (const char*)As + row_a * 128 + (((2 * kg + 1) ^ (row_a & 7)) << 4);
    const char* pBe = (const char*)Bs + row_b * 128 + ((( 2 * kg    ) ^ (row_b & 7)) << 4);
    const char* pBo = (const char*)Bs + row_b * 128 + (((2 * kg + 1) ^ (row_b & 7)) << 4);

    f32x4 acc[8][4];
#pragma unroll
    for (int i = 0; i < 8; ++i)
#pragma unroll
        for (int j = 0; j < 4; ++j) acc[i][j] = (f32x4){0.f, 0.f, 0.f, 0.f};

    // prologue: stage tile 0 (B then A — issue order defines vmcnt ages), drain, barrier
#pragma unroll
    for (int j = 0; j < 4; ++j)
        gload16(bgp + (size_t)(j * 32) * HD, bLdst + j * 4096);
#pragma unroll
    for (int j = 0; j < 4; ++j)
        gload16(agp + (size_t)(j * 32) * HD, aLdst + j * 4096);
    SBAR; asm volatile("s_waitcnt vmcnt(0)" ::: "memory"); SBAR;
    __builtin_amdgcn_s_barrier();
    SBAR;

    for (int t2 = 0; t2 < KT8; t2 += 2) {
        tile8_body<0>(t2,     agp, bgp, aLdst, bLdst, pAe, pAo, pBe, pBo, acc);
        tile8_body<1>(t2 + 1, agp, bgp, aLdst, bLdst, pAe, pAo, pBe, pBo, acc);
    }

    // ---- epilogue: bias, per-row max/sumexp over this wave's 64 cols ----
    float bv4[4];
#pragma unroll
    for (int ni = 0; ni < 4; ++ni) bv4[ni] = bias[c0 + wc * 64 + ni * 16 + lane15];

#pragma unroll
    for (int mi = 0; mi < 8; ++mi) {
        const int grow_base = row0 + wr * 128 + mi * 16 + kg * 4;
#pragma unroll
        for (int j = 0; j < 4; ++j) {
            const int grow = grow_base + j;
            float v[4];
#pragma unroll
            for (int ni = 0; ni < 4; ++ni) v[ni] = acc[mi][ni][j] + bv4[ni];
            float m = fmaxf(fmaxf(v[0], v[1]), fmaxf(v[2], v[3]));
#pragma unroll
            for (int msk = 1; msk < 16; msk <<= 1)
                m = fmaxf(m, __shfl_xor(m, msk));
            float s = __expf(v[0] - m) + __expf(v[1] - m) +
                      __expf(v[2] - m) + __expf(v[3] - m);
#pragma unroll
            for (int msk = 1; msk < 16; msk <<= 1)
                s += __shfl_xor(s, msk);
            const int tg = target[grow];
#pragma unroll
            for (int ni = 0; ni < 4; ++ni) {
                const int gcol = c0 + wc * 64 + ni * 16 + lane15;
                if (tg == gcol) tgtlog[model * BT + grow] = v[ni];
            }
            if (lane15 == 0) {
                const size_t po = ((size_t)(model * BT + grow) * NCHUNK + nb * 4 + wc) * 2;
                partials[po]     = m;
                partials[po + 1] = s;
            }
        }
    }
}

// ---------------- kernel 0a-fallback: convert x f32 -> bf16 ----------------
__global__ void convert_x(const float* __restrict__ x0, const float* __restrict__ x1,
                          uint16_t* __restrict__ xbf) {
    const int64_t n4 = (int64_t)BT * HD / 4;
    ushort4* o0 = (ushort4*)xbf;
    ushort4* o1 = (ushort4*)(xbf + (int64_t)BT * HD);
    for (int64_t i = blockIdx.x * (int64_t)blockDim.x + threadIdx.x; i < n4;
         i += (int64_t)gridDim.x * blockDim.x) {
        float4 a = ((const float4*)x0)[i];
        float4 b = ((const float4*)x1)[i];
        ushort4 ua, ub;
        ua.x = f2bf(a.x); ua.y = f2bf(a.y); ua.z = f2bf(a.z); ua.w = f2bf(a.w);
        ub.x = f2bf(b.x); ub.y = f2bf(b.y); ub.z = f2bf(b.z); ub.w = f2bf(b.w);
        o0[i] = ua;
        o1[i] = ub;
    }
}

// ---------------- kernel 1 (fallback, f32 weights): R1 structure ----------------
__global__ __launch_bounds__(256) void gemm_lse_f32(
    const uint16_t* __restrict__ xbf,
    const float* __restrict__ w0, const float* __restrict__ b0,
    const float* __restrict__ w1, const float* __restrict__ b1,
    const int* __restrict__ target,
    float* __restrict__ partials, float* __restrict__ tgtlog)
{
    const int orig = blockIdx.x;               // grid 8000
    const int wgid = (orig & 7) * 1000 + (orig >> 3);
    const int mb    = wgid & 7;
    const int rest  = wgid >> 3;
    const int chunk = rest % 500;
    const int model = rest / 500;

    const float* w    = model ? w1 : w0;
    const float* bias = model ? b1 : b0;
    const uint16_t* xb = xbf + (size_t)model * BT * HD;

    const int row0 = mb * 256;
    const int c0   = chunk * 64;

    const int tid  = threadIdx.x;
    const int lane = tid & 63;
    const int wid  = tid >> 6;

    __shared__ uint16_t As_[256 * 64];
    __shared__ uint16_t Bs_[64 * 64];

    f32x4 acc[4][4];
#pragma unroll
    for (int i = 0; i < 4; ++i)
#pragma unroll
        for (int j = 0; j < 4; ++j) acc[i][j] = (f32x4){0.f, 0.f, 0.f, 0.f};

    const int srow8 = lane >> 3;
    const int slot  = (lane & 7) ^ srow8;
    const uint16_t* agsrc = xb + (size_t)(row0 + wid * 64 + srow8) * HD + slot * 8;
    char* aldst = (char*)As_ + wid * 8192;

    const int ss   = tid & 7;
    const int srow = tid >> 3;
    const int swz_w = (srow & 7) << 4;
    const float* bptr = w + (size_t)(c0 + srow) * HD + ss * 8;

    const int lane15 = lane & 15;
    const int kg     = lane >> 4;
    const int swz_r  = (lane & 7) << 4;

    for (int kt = 0; kt < 64; ++kt) {
        const int kofs = kt * 64;
#pragma unroll
        for (int c = 0; c < 8; ++c)
            gload16(agsrc + (size_t)c * 8 * HD + kofs, aldst + c * 1024);
        {
            float4 bv[2][2];
#pragma unroll
            for (int r = 0; r < 2; ++r) {
                const float* p = bptr + (size_t)r * 32 * HD + kofs;
                bv[r][0] = *(const float4*)(p);
                bv[r][1] = *(const float4*)(p + 4);
            }
#pragma unroll
            for (int r = 0; r < 2; ++r) {
                const int row_l = srow + r * 32;
                float fv[8] = {bv[r][0].x, bv[r][0].y, bv[r][0].z, bv[r][0].w,
                               bv[r][1].x, bv[r][1].y, bv[r][1].z, bv[r][1].w};
                uint32_t pk[4];
#pragma unroll
                for (int e = 0; e < 4; ++e)
                    pk[e] = (uint32_t)f2bf(fv[2 * e]) | ((uint32_t)f2bf(fv[2 * e + 1]) << 16);
                const int off = (row_l * 128 + ss * 16) ^ swz_w;
                *(uint4*)((char*)Bs_ + off) = *(uint4*)pk;
            }
        }
        __syncthreads();
#pragma unroll
        for (int ks = 0; ks < 2; ++ks) {
            short8 af[4], bf[4];
#pragma unroll
            for (int mi = 0; mi < 4; ++mi) {
                const int arow = wid * 64 + mi * 16 + lane15;
                const int off = (arow * 128 + ks * 64 + kg * 16) ^ swz_r;
                af[mi] = *(const short8*)((const char*)As_ + off);
            }
#pragma unroll
            for (int ni = 0; ni < 4; ++ni) {
                const int brow = ni * 16 + lane15;
                const int off = (brow * 128 + ks * 64 + kg * 16) ^ swz_r;
                bf[ni] = *(const short8*)((const char*)Bs_ + off);
            }
#pragma unroll
            for (int mi = 0; mi < 4; ++mi)
#pragma unroll
                for (int ni = 0; ni < 4; ++ni)
                    acc[mi][ni] = __builtin_amdgcn_mfma_f32_16x16x32_bf16(
                        af[mi], bf[ni], acc[mi][ni], 0, 0, 0);
        }
        __syncthreads();
    }

    float bv4[4];
#pragma unroll
    for (int ni = 0; ni < 4; ++ni) bv4[ni] = bias[c0 + ni * 16 + lane15];

#pragma unroll
    for (int mi = 0; mi < 4; ++mi) {
        const int grow_base = row0 + wid * 64 + mi * 16 + kg * 4;
#pragma unroll
        for (int j = 0; j < 4; ++j) {
            const int grow = grow_base + j;
            float v[4];
#pragma unroll
            for (int ni = 0; ni < 4; ++ni) v[ni] = acc[mi][ni][j] + bv4[ni];
            float m = fmaxf(fmaxf(v[0], v[1]), fmaxf(v[2], v[3]));
#pragma unroll
            for (int msk = 1; msk < 16; msk <<= 1)
                m = fmaxf(m, __shfl_xor(m, msk));
            float s = __expf(v[0] - m) + __expf(v[1] - m) +
                      __expf(v[2] - m) + __expf(v[3] - m);
#pragma unroll
            for (int msk = 1; msk < 16; msk <<= 1)
                s += __shfl_xor(s, msk);
            const int tg = target[grow];
#pragma unroll
            for (int ni = 0; ni < 4; ++ni) {
                const int gcol = c0 + ni * 16 + lane15;
                if (tg == gcol) tgtlog[model * BT + grow] = v[ni];
            }
            if (lane15 == 0) {
                const size_t po = ((size_t)(model * BT + grow) * NCHUNK + chunk) * 2;
                partials[po]     = m;
                partials[po + 1] = s;
            }
        }
    }
}

// ---------------- kernel 2: combine chunk partials -> lse -> per-token logp ----------------
__global__ void lse_reduce(const float* __restrict__ partials,
                           const float* __restrict__ tgtlog,
                           float* __restrict__ logp) {
    const int gw = blockIdx.x * (blockDim.x >> 6) + (threadIdx.x >> 6);
    if (gw >= 2 * BT) return;
    const int lane = threadIdx.x & 63;
    const float* p = partials + (size_t)gw * NCHUNK * 2;

    float m = -1e30f;
#pragma unroll
    for (int i = 0; i < 8; ++i) {
        const int c = lane + i * 64;
        if (c < NCHUNK) m = fmaxf(m, p[c * 2]);
    }
#pragma unroll
    for (int msk = 1; msk < 64; msk <<= 1) m = fmaxf(m, __shfl_xor(m, msk));
    float s = 0.f;
#pragma unroll
    for (int i = 0; i < 8; ++i) {
        const int c = lane + i * 64;
        if (c < NCHUNK) s += p[c * 2 + 1] * __expf(p[c * 2] - m);
    }
#pragma unroll
    for (int msk = 1; msk < 64; msk <<= 1) s += __shfl_xor(s, msk);
    if (lane == 0) {
        const float lse = m + __logf(s);
        logp[gw] = tgtlog[gw] - lse;
    }
}

// ---------------- kernel 3: KTO loss ----------------
__global__ void final_loss(const float* __restrict__ logp, const int* __restrict__ target,
                           const int* __restrict__ pref, const float* __restrict__ kl,
                           float* __restrict__ out) {
    const int t = threadIdx.x;          // 512 threads
    const int lane = t & 63, wv = t >> 6;
    __shared__ float rp[4][8], rr[4][8], rm[4][8];
#pragma unroll
    for (int b = 0; b < 4; ++b) {
        const int idx = b * TT + t;
        const int tg = target[idx];
        const bool mk = (tg != IGNORE_IDX);
        float lp = mk ? logp[idx] : 0.f;
        float lr = mk ? logp[BT + idx] : 0.f;
        float mc = mk ? 1.f : 0.f;
        for (int off = 32; off; off >>= 1) {
            lp += __shfl_down(lp, off);
            lr += __shfl_down(lr, off);
            mc += __shfl_down(mc, off);
        }
        if (lane == 0) { rp[b][wv] = lp; rr[b][wv] = lr; rm[b][wv] = mc; }
    }
    __syncthreads();
    if (t == 0) {
        float loss = 0.f;
        for (int b = 0; b < 4; ++b) {
            float sp = 0.f, sr = 0.f, sm = 0.f;
            for (int i = 0; i < 8; ++i) { sp += rp[b][i]; sr += rr[b][i]; sm += rm[b][i]; }
            const float denom = fmaxf(sm, 1.f);
            const float lrb = (sp - sr) / denom;
            const float mult = pref[b] ? 1.f : -1.f;
            const float z = 0.1f * (lrb - kl[0]) * mult;
            loss += 1.f / (1.f + __expf(z));   // 1 - sigmoid(z)
        }
        out[0] = loss * 0.25f;
    }
}

extern "C" void kernel_launch(void* const* d_in, const int* in_sizes, int n_in,
                              void* d_out, int out_size, void* d_ws, size_t ws_size,
                              hipStream_t stream) {
    const float* x    = (const float*)d_in[0];
    const float* w0   = (const float*)d_in[1];
    const float* b0   = (const float*)d_in[2];
    const int*   tgt  = (const int*)d_in[3];
    const int*   pref = (const int*)d_in[4];
    const float* xr   = (const float*)d_in[5];
    const float* w1   = (const float*)d_in[6];
    const float* b1   = (const float*)d_in[7];
    const float* kl   = (const float*)d_in[8];
    float* out = (float*)d_out;

    // ws layout: partials | tgtlog | logp | then path-specific:
    //   fp8: xq (16.8MB) | wq (262MB)     fallback: xbf (33.6MB)
    const size_t part_b = (size_t)2 * BT * NCHUNK * 2 * 4;  // 16.38 MB
    const size_t tl_b   = (size_t)2 * BT * 4;
    const size_t xq_b   = (size_t)2 * BT * HD;              // 16.78 MB
    const size_t wq_b   = (size_t)2 * VD * HD;              // 262.1 MB

    char* wp = (char*)d_ws;
    float*   partials = (float*)wp;                  wp += part_b;
    float*   tgtlog   = (float*)wp;                  wp += tl_b;
    float*   logp     = (float*)wp;                  wp += tl_b;
    uint8_t* xq       = (uint8_t*)wp;
    uint8_t* wq       = xq + xq_b;
    uint16_t* xbf     = (uint16_t*)wp;

    const bool use_fp8 = ws_size >= (part_b + 2 * tl_b + xq_b + wq_b);

    if (use_fp8) {
        hipLaunchKernelGGL(convert_x_fp8, dim3(512), dim3(256), 0, stream, x, xr, xq);
        hipLaunchKernelGGL(convert_w_fp8, dim3(4096), dim3(256), 0, stream, w0, w1, wq);
        hipLaunchKernelGGL(gemm_lse_fp8, dim3(NWG2), dim3(512), 0, stream,
                           xq, wq, b0, b1, tgt, partials, tgtlog);
    } else {
        hipLaunchKernelGGL(convert_x, dim3(1024), dim3(256), 0, stream, x, xr, xbf);
        hipLaunchKernelGGL(gemm_lse_f32, dim3(8000), dim3(256), 0, stream,
                           xbf, w0, b0, w1, b1, tgt, partials, tgtlog);
    }
    hipLaunchKernelGGL(lse_reduce, dim3(2 * BT / 4), dim3(256), 0, stream,
                       partials, tgtlog, logp);
    hipLaunchKernelGGL(final_loss, dim3(1), dim3(512), 0, stream, logp, tgt, pref, kl, out);
}